// Round 1
// baseline (1092.426 us; speedup 1.0000x reference)
//
#include <hip/hip_runtime.h>

#define BATCH 8
#define NROW 4096
#define MCOL 4096
#define DDIM 128
#define RATIO2 0.64f   // 0.8^2
#define DIST2  0.49f   // 0.7^2

typedef __attribute__((ext_vector_type(8))) short bf16x8;
typedef __attribute__((ext_vector_type(4))) float floatx4;

__device__ inline unsigned short f2bf(float f) {
    union { float f; unsigned int u; } v; v.f = f;
    unsigned int r = (v.u + 0x7FFFu + ((v.u >> 16) & 1u)) >> 16;   // RNE
    return (unsigned short)r;
}

// better(candidate v,i  vs  incumbent v2,i2) with jax top_k tie semantics
// (equal values -> lower index wins)
__device__ inline bool better(float v, int i, float v2, int i2) {
    return (v > v2) || (v == v2 && i < i2);
}

// ---------------- inverse norms ----------------
__global__ void norms_kernel(const float* __restrict__ d0, const float* __restrict__ d1,
                             float* __restrict__ inv0, float* __restrict__ inv1) {
    int row = blockIdx.x * 4 + (threadIdx.x >> 6);
    int lane = threadIdx.x & 63;
    const float* src; float* dst; int r;
    if (row < BATCH * NROW) { src = d0; dst = inv0; r = row; }
    else                    { src = d1; dst = inv1; r = row - BATCH * NROW; }
    float2 v = *(const float2*)&src[(size_t)r * DDIM + lane * 2];
    float ss = v.x * v.x + v.y * v.y;
    #pragma unroll
    for (int off = 32; off > 0; off >>= 1) ss += __shfl_xor(ss, off);
    if (lane == 0) {
        float n = fmaxf(sqrtf(ss), 1e-12f);
        dst[r] = 1.0f / n;
    }
}

// ---------------- bf16 MFMA GEMM: sim = d0n @ d1n^T ----------------
// 128x128 tile per block, K=128 fully resident in LDS.
// LDS layout XOR-swizzled at 16B-chunk granularity: element (row,k) lives at
// row*128 + ((k/8) ^ (row&7))*8 + (k%8)  -> fragment reads and staging writes
// are both <=2-way bank conflicted (free).
__device__ inline int lds_off(int row, int k) {
    return row * 128 + (((k >> 3) ^ (row & 7)) << 3) + (k & 7);
}

__global__ __launch_bounds__(256, 2)
void gemm_kernel(const float* __restrict__ d0, const float* __restrict__ d1,
                 const float* __restrict__ inv0, const float* __restrict__ inv1,
                 float* __restrict__ sim) {
    __shared__ unsigned short As[128 * 128];   // 32 KB
    __shared__ unsigned short Bs[128 * 128];   // 32 KB
    const int b  = blockIdx.z;
    const int n0 = blockIdx.y * 128;
    const int m0 = blockIdx.x * 128;
    const int tid = threadIdx.x;

    // stage + normalize + cast to bf16
    #pragma unroll
    for (int i = 0; i < 16; ++i) {
        int f  = tid + i * 256;   // float4 slot 0..4095
        int r  = f >> 5;          // tile row
        int k4 = f & 31;          // float4 index along K
        {
            float4 v = *(const float4*)&d0[((size_t)(b * NROW + n0 + r)) * DDIM + k4 * 4];
            float s = inv0[b * NROW + n0 + r];
            ushort4 w;
            w.x = f2bf(v.x * s); w.y = f2bf(v.y * s);
            w.z = f2bf(v.z * s); w.w = f2bf(v.w * s);
            *(ushort4*)&As[lds_off(r, k4 * 4)] = w;
        }
        {
            float4 v = *(const float4*)&d1[((size_t)(b * MCOL + m0 + r)) * DDIM + k4 * 4];
            float s = inv1[b * MCOL + m0 + r];
            ushort4 w;
            w.x = f2bf(v.x * s); w.y = f2bf(v.y * s);
            w.z = f2bf(v.z * s); w.w = f2bf(v.w * s);
            *(ushort4*)&Bs[lds_off(r, k4 * 4)] = w;
        }
    }
    __syncthreads();

    const int wave = tid >> 6;
    const int lane = tid & 63;
    const int quad = lane >> 4;
    const int l15  = lane & 15;
    const int wr = (wave >> 1) * 64;   // wave's 64x64 quadrant
    const int wc = (wave & 1) * 64;

    floatx4 acc[4][4];
    #pragma unroll
    for (int i = 0; i < 4; ++i)
        #pragma unroll
        for (int j = 0; j < 4; ++j)
            acc[i][j] = (floatx4){0.f, 0.f, 0.f, 0.f};

    #pragma unroll
    for (int k0 = 0; k0 < 128; k0 += 32) {
        bf16x8 af[4], bf[4];
        #pragma unroll
        for (int i = 0; i < 4; ++i)
            af[i] = *(const bf16x8*)&As[lds_off(wr + i * 16 + l15, k0 + quad * 8)];
        #pragma unroll
        for (int j = 0; j < 4; ++j)
            bf[j] = *(const bf16x8*)&Bs[lds_off(wc + j * 16 + l15, k0 + quad * 8)];
        #pragma unroll
        for (int i = 0; i < 4; ++i)
            #pragma unroll
            for (int j = 0; j < 4; ++j)
                acc[i][j] = __builtin_amdgcn_mfma_f32_16x16x32_bf16(af[i], bf[j], acc[i][j], 0, 0, 0);
    }

    // epilogue: C/D layout col = lane&15, row = quad*4 + reg
    #pragma unroll
    for (int i = 0; i < 4; ++i) {
        int n = n0 + wr + i * 16 + quad * 4;
        #pragma unroll
        for (int j = 0; j < 4; ++j) {
            int m = m0 + wc + j * 16 + l15;
            size_t base = ((size_t)(b * NROW + n)) * MCOL + m;
            sim[base]            = acc[i][j][0];
            sim[base + MCOL]     = acc[i][j][1];
            sim[base + 2 * MCOL] = acc[i][j][2];
            sim[base + 3 * MCOL] = acc[i][j][3];
        }
    }
}

// ---------------- row top-2 (matches0 candidates) ----------------
__global__ void row_top2_kernel(const float* __restrict__ sim, int* __restrict__ m0w) {
    const int row = blockIdx.x;            // b*NROW + n
    const float* p = sim + (size_t)row * MCOL;
    const int t = threadIdx.x;
    float v1 = -2e30f, v2 = -2e30f; int i1 = -1, i2 = -1;
    #pragma unroll
    for (int j = 0; j < MCOL / 256; ++j) {
        int m = t + j * 256;
        float v = p[m];
        if (better(v, m, v1, i1)) { v2 = v1; i2 = i1; v1 = v; i1 = m; }
        else if (better(v, m, v2, i2)) { v2 = v; i2 = m; }
    }
    __shared__ float sv1[256], sv2[256];
    __shared__ int   si1[256], si2[256];
    sv1[t] = v1; sv2[t] = v2; si1[t] = i1; si2[t] = i2;
    __syncthreads();
    for (int s = 128; s > 0; s >>= 1) {
        if (t < s) {
            float a1 = sv1[t], a2 = sv2[t]; int ai1 = si1[t], ai2 = si2[t];
            float b1 = sv1[t + s], b2 = sv2[t + s]; int bi1 = si1[t + s], bi2 = si2[t + s];
            float n1, n2; int ni1, ni2;
            if (better(a1, ai1, b1, bi1)) {
                n1 = a1; ni1 = ai1;
                if (better(a2, ai2, b1, bi1)) { n2 = a2; ni2 = ai2; }
                else                          { n2 = b1; ni2 = bi1; }
            } else {
                n1 = b1; ni1 = bi1;
                if (better(b2, bi2, a1, ai1)) { n2 = b2; ni2 = bi2; }
                else                          { n2 = a1; ni2 = ai1; }
            }
            sv1[t] = n1; sv2[t] = n2; si1[t] = ni1; si2[t] = ni2;
        }
        __syncthreads();
    }
    if (t == 0) {
        float dd1 = 2.0f * (1.0f - sv1[0]);
        float dd2 = 2.0f * (1.0f - sv2[0]);
        bool ok = (dd1 <= RATIO2 * dd2) && (dd1 <= DIST2);
        m0w[row] = ok ? si1[0] : -1;
    }
}

// ---------------- column top-2, split over n for parallelism ----------------
__global__ void col_top2_kernel(const float* __restrict__ sim,
                                float2* __restrict__ pv, int2* __restrict__ pidx) {
    const int m  = blockIdx.x * 256 + threadIdx.x;
    const int ns = blockIdx.y;   // 0..7
    const int b  = blockIdx.z;
    const float* base = sim + (size_t)b * NROW * MCOL + m;
    float v1 = -2e30f, v2 = -2e30f; int i1 = -1, i2 = -1;
    const int nbeg = ns * (NROW / 8);
    for (int n = nbeg; n < nbeg + NROW / 8; ++n) {
        float v = base[(size_t)n * MCOL];
        if (better(v, n, v1, i1)) { v2 = v1; i2 = i1; v1 = v; i1 = n; }
        else if (better(v, n, v2, i2)) { v2 = v; i2 = n; }
    }
    int idx = (b * MCOL + m) * 8 + ns;
    pv[idx]   = make_float2(v1, v2);
    pidx[idx] = make_int2(i1, i2);
}

__global__ void col_merge_kernel(const float2* __restrict__ pv, const int2* __restrict__ pidx,
                                 int* __restrict__ m1w) {
    int idx = blockIdx.x * 256 + threadIdx.x;   // b*MCOL + m
    float v1 = -2e30f, v2 = -2e30f; int i1 = -1, i2 = -1;
    #pragma unroll
    for (int s = 0; s < 8; ++s) {
        float2 pvv = pv[idx * 8 + s];
        int2   pii = pidx[idx * 8 + s];
        if (better(pvv.x, pii.x, v1, i1)) {
            float ov = v1; int oi = i1;
            v1 = pvv.x; i1 = pii.x;
            if (better(pvv.y, pii.y, ov, oi)) { v2 = pvv.y; i2 = pii.y; }
            else                              { v2 = ov;    i2 = oi; }
        } else if (better(pvv.x, pii.x, v2, i2)) {
            v2 = pvv.x; i2 = pii.x;
        }
    }
    float dd1 = 2.0f * (1.0f - v1);
    float dd2 = 2.0f * (1.0f - v2);
    bool ok = (dd1 <= RATIO2 * dd2) && (dd1 <= DIST2);
    m1w[idx] = ok ? i1 : -1;
}

// ---------------- mutual check + write small outputs ----------------
__global__ void mutual_kernel(const int* __restrict__ m0w, const int* __restrict__ m1w,
                              float* __restrict__ out) {
    int i = blockIdx.x * 256 + threadIdx.x;   // 0..32767
    int b = i >> 12, x = i & 4095;
    int m0 = m0w[i];
    int r0 = (m0 > -1 && m1w[(b << 12) + m0] == x) ? m0 : -1;
    int m1 = m1w[i];
    int r1 = (m1 > -1 && m0w[(b << 12) + m1] == x) ? m1 : -1;
    out[i]                 = (float)r0;       // matches0
    out[32768 + i]         = (float)r1;       // matches1
    out[65536 + i]         = (r0 > -1) ? 1.0f : 0.0f;   // mscores0
    out[98304 + i]         = (r1 > -1) ? 1.0f : 0.0f;   // mscores1
}

extern "C" void kernel_launch(void* const* d_in, const int* in_sizes, int n_in,
                              void* d_out, int out_size, void* d_ws, size_t ws_size,
                              hipStream_t stream) {
    const float* d0 = (const float*)d_in[0];
    const float* d1 = (const float*)d_in[1];
    float* out = (float*)d_out;
    float* sim = out + 4 * BATCH * NROW;      // sim after the 4 small outputs

    // workspace layout (floats/ints are 4B):
    float*  inv0 = (float*)d_ws;                       // 32768
    float*  inv1 = inv0 + BATCH * NROW;                // 32768
    int*    m0w  = (int*)(inv1 + BATCH * MCOL);        // 32768
    int*    m1w  = m0w + BATCH * NROW;                 // 32768
    float2* pv   = (float2*)(m1w + BATCH * MCOL);      // 32768*8 float2 (2MB)
    int2*   pidx = (int2*)(pv + BATCH * MCOL * 8);     // 32768*8 int2   (2MB)

    norms_kernel<<<(BATCH * (NROW + MCOL)) / 4, 256, 0, stream>>>(d0, d1, inv0, inv1);
    gemm_kernel<<<dim3(MCOL / 128, NROW / 128, BATCH), 256, 0, stream>>>(d0, d1, inv0, inv1, sim);
    row_top2_kernel<<<BATCH * NROW, 256, 0, stream>>>(sim, m0w);
    col_top2_kernel<<<dim3(MCOL / 256, 8, BATCH), 256, 0, stream>>>(sim, pv, pidx);
    col_merge_kernel<<<BATCH * MCOL / 256, 256, 0, stream>>>(pv, pidx, m1w);
    mutual_kernel<<<BATCH * NROW / 256, 256, 0, stream>>>(m0w, m1w, out);
}